// Round 1
// baseline (1502.445 us; speedup 1.0000x reference)
//
#include <hip/hip_runtime.h>
#include <stdint.h>

typedef unsigned short u16;
typedef __attribute__((ext_vector_type(8))) short s16x8;   // 8 bf16 (4 VGPRs) MFMA frag
typedef __attribute__((ext_vector_type(4))) float f32x4;   // MFMA acc
typedef __attribute__((ext_vector_type(4))) unsigned short u16x4;

#define MFMA_BF16(a, b, c) __builtin_amdgcn_mfma_f32_16x16x32_bf16((a), (b), (c), 0, 0, 0)

__device__ __forceinline__ u16 f2bf(float f) {  // fp32 -> bf16 RNE
  uint32_t u = __float_as_uint(f);
  u += 0x7fffu + ((u >> 16) & 1u);
  return (u16)(u >> 16);
}

// ---- convert fp32 -> bf16, 4 elems/thread ----
__global__ void cvt_f32_bf16(const float* __restrict__ in, u16* __restrict__ out, int n4) {
  int i = blockIdx.x * blockDim.x + threadIdx.x;
  if (i >= n4) return;
  float4 v = ((const float4*)in)[i];
  u16x4 o = { f2bf(v.x), f2bf(v.y), f2bf(v.z), f2bf(v.w) };
  ((u16x4*)out)[i] = o;
}

// ---- transpose [R][C] fp32 -> [C][R] bf16 ----
__global__ void transpose_cvt(const float* __restrict__ in, u16* __restrict__ out, int R, int C) {
  __shared__ float tile[32][33];
  int c0 = blockIdx.x * 32, r0 = blockIdx.y * 32;
  int tx = threadIdx.x, ty = threadIdx.y;
#pragma unroll
  for (int i = 0; i < 32; i += 8)
    tile[ty + i][tx] = in[(size_t)(r0 + ty + i) * C + c0 + tx];
  __syncthreads();
#pragma unroll
  for (int i = 0; i < 32; i += 8)
    out[(size_t)(c0 + ty + i) * R + r0 + tx] = f2bf(tile[tx][ty + i]);
}

// ---- GEMM1: x[8192x1024] @ WqkvT -> scatter to q[bh][s][d], k[bh][s][d], vT[bh][d][s] (bf16) ----
__global__ __launch_bounds__(256) void gemm_qkv(
    const u16* __restrict__ A, const u16* __restrict__ Bt, const float* __restrict__ bias,
    u16* __restrict__ qb, u16* __restrict__ kb, u16* __restrict__ vTb) {
  __shared__ alignas(16) u16 sA[128][40];
  __shared__ alignas(16) u16 sB[128][40];
  const int tid = threadIdx.x;
  const int w = tid >> 6, lane = tid & 63, quad = lane >> 4, l15 = lane & 15;
  const int m0 = blockIdx.x * 128, n0 = blockIdx.y * 128;
  const int mw = (w & 1) * 64, nw = (w >> 1) * 64;
  const f32x4 fz = {0.f, 0.f, 0.f, 0.f};
  f32x4 acc[4][4];
#pragma unroll
  for (int i = 0; i < 4; i++)
#pragma unroll
    for (int j = 0; j < 4; j++) acc[i][j] = fz;
  const int sr = tid >> 2, sc = (tid & 3) * 8;
  const u16* Ab = A + (size_t)(m0 + sr) * 1024 + sc;
  const u16* Bb = Bt + (size_t)(n0 + sr) * 1024 + sc;
  for (int k0 = 0; k0 < 1024; k0 += 32) {
    __syncthreads();
    *(s16x8*)&sA[sr][sc]      = *(const s16x8*)(Ab + k0);
    *(s16x8*)&sA[sr + 64][sc] = *(const s16x8*)(Ab + 64 * 1024 + k0);
    *(s16x8*)&sB[sr][sc]      = *(const s16x8*)(Bb + k0);
    *(s16x8*)&sB[sr + 64][sc] = *(const s16x8*)(Bb + 64 * 1024 + k0);
    __syncthreads();
    s16x8 af[4], bf[4];
#pragma unroll
    for (int i = 0; i < 4; i++) af[i] = *(const s16x8*)&sA[mw + i * 16 + l15][quad * 8];
#pragma unroll
    for (int j = 0; j < 4; j++) bf[j] = *(const s16x8*)&sB[nw + j * 16 + l15][quad * 8];
#pragma unroll
    for (int i = 0; i < 4; i++)
#pragma unroll
      for (int j = 0; j < 4; j++)
        acc[i][j] = MFMA_BF16(af[i], bf[j], acc[i][j]);
  }
#pragma unroll
  for (int j = 0; j < 4; j++) {
    const int ng = n0 + nw + j * 16 + l15;
    const float bv = bias[ng];
    const int h = ng / 192, jj = ng - h * 192;
#pragma unroll
    for (int i = 0; i < 4; i++) {
#pragma unroll
      for (int r = 0; r < 4; r++) {
        const int mg = m0 + mw + i * 16 + quad * 4 + r;
        const int b = mg >> 11, s = mg & 2047;
        const int bh = b * 16 + h;
        const u16 val = f2bf(acc[i][j][r] + bv);
        if (jj < 64)       qb[((size_t)bh * 2048 + s) * 64 + jj] = val;
        else if (jj < 128) kb[((size_t)bh * 2048 + s) * 64 + (jj - 64)] = val;
        else               vTb[((size_t)bh * 64 + (jj - 128)) * 2048 + s] = val;
      }
    }
  }
}

// ---- fused attention: QK^T -> softmax (2-pass online) -> write attn fp32 -> PV ----
__global__ __launch_bounds__(256) void attention_k(
    const u16* __restrict__ qb, const u16* __restrict__ kb, const u16* __restrict__ vTb,
    float* __restrict__ attn, u16* __restrict__ vals) {
  __shared__ alignas(16) u16 sQ[128][72];
  __shared__ alignas(16) u16 sK[64][72];
  __shared__ alignas(16) u16 sVt[64][72];
  __shared__ alignas(16) u16 sP[4][32][72];
  const int tid = threadIdx.x;
  const int w = tid >> 6, lane = tid & 63, quad = lane >> 4, l15 = lane & 15;
  const int bh = blockIdx.y;
  const int q0 = blockIdx.x * 128;
  const size_t qko = (size_t)bh * 2048 * 64;
  const f32x4 fz = {0.f, 0.f, 0.f, 0.f};

  { // stage Q tile [128][64]
    int r = tid >> 1, c = (tid & 1) * 32;
    const u16* g = qb + qko + (size_t)(q0 + r) * 64 + c;
    *(s16x8*)&sQ[r][c]      = *(const s16x8*)(g);
    *(s16x8*)&sQ[r][c + 8]  = *(const s16x8*)(g + 8);
    *(s16x8*)&sQ[r][c + 16] = *(const s16x8*)(g + 16);
    *(s16x8*)&sQ[r][c + 24] = *(const s16x8*)(g + 24);
  }

  float m_s[2][4], l_s[2][4];
#pragma unroll
  for (int t = 0; t < 2; t++)
#pragma unroll
    for (int r = 0; r < 4; r++) { m_s[t][r] = -1e30f; l_s[t][r] = 0.f; }

  const int sr = tid >> 2, sc = (tid & 3) * 16;

  // ---- pass 1: running (m, l) ----
  for (int k0 = 0; k0 < 2048; k0 += 64) {
    __syncthreads();
    {
      const u16* g = kb + qko + (size_t)(k0 + sr) * 64 + sc;
      *(s16x8*)&sK[sr][sc]     = *(const s16x8*)(g);
      *(s16x8*)&sK[sr][sc + 8] = *(const s16x8*)(g + 8);
    }
    __syncthreads();
    f32x4 sa[2][4];
#pragma unroll
    for (int t = 0; t < 2; t++)
#pragma unroll
      for (int n = 0; n < 4; n++) sa[t][n] = fz;
#pragma unroll
    for (int kk = 0; kk < 2; kk++) {
      s16x8 aq0 = *(const s16x8*)&sQ[w * 32 + l15][kk * 32 + quad * 8];
      s16x8 aq1 = *(const s16x8*)&sQ[w * 32 + 16 + l15][kk * 32 + quad * 8];
#pragma unroll
      for (int n = 0; n < 4; n++) {
        s16x8 bk = *(const s16x8*)&sK[n * 16 + l15][kk * 32 + quad * 8];
        sa[0][n] = MFMA_BF16(aq0, bk, sa[0][n]);
        sa[1][n] = MFMA_BF16(aq1, bk, sa[1][n]);
      }
    }
#pragma unroll
    for (int t = 0; t < 2; t++)
#pragma unroll
      for (int r = 0; r < 4; r++) {
        float mx = fmaxf(fmaxf(sa[t][0][r], sa[t][1][r]), fmaxf(sa[t][2][r], sa[t][3][r])) * 0.125f;
#pragma unroll
        for (int off = 8; off; off >>= 1) mx = fmaxf(mx, __shfl_xor(mx, off));
        float mo = m_s[t][r];
        float mn = fmaxf(mo, mx);
        float sum = 0.f;
#pragma unroll
        for (int n = 0; n < 4; n++) sum += __expf(sa[t][n][r] * 0.125f - mn);
#pragma unroll
        for (int off = 8; off; off >>= 1) sum += __shfl_xor(sum, off);
        l_s[t][r] = l_s[t][r] * __expf(mo - mn) + sum;
        m_s[t][r] = mn;
      }
  }

  float inv_l[2][4];
#pragma unroll
  for (int t = 0; t < 2; t++)
#pragma unroll
    for (int r = 0; r < 4; r++) inv_l[t][r] = 1.0f / l_s[t][r];

  f32x4 oa[2][4];
#pragma unroll
  for (int t = 0; t < 2; t++)
#pragma unroll
    for (int d = 0; d < 4; d++) oa[t][d] = fz;

  // ---- pass 2: recompute logits, write probs, accumulate P.V ----
  for (int k0 = 0; k0 < 2048; k0 += 64) {
    __syncthreads();
    {
      const u16* g = kb + qko + (size_t)(k0 + sr) * 64 + sc;
      *(s16x8*)&sK[sr][sc]     = *(const s16x8*)(g);
      *(s16x8*)&sK[sr][sc + 8] = *(const s16x8*)(g + 8);
      const u16* g2 = vTb + (size_t)bh * 64 * 2048 + (size_t)sr * 2048 + k0 + sc;
      *(s16x8*)&sVt[sr][sc]     = *(const s16x8*)(g2);
      *(s16x8*)&sVt[sr][sc + 8] = *(const s16x8*)(g2 + 8);
    }
    __syncthreads();
    f32x4 sa[2][4];
#pragma unroll
    for (int t = 0; t < 2; t++)
#pragma unroll
      for (int n = 0; n < 4; n++) sa[t][n] = fz;
#pragma unroll
    for (int kk = 0; kk < 2; kk++) {
      s16x8 aq0 = *(const s16x8*)&sQ[w * 32 + l15][kk * 32 + quad * 8];
      s16x8 aq1 = *(const s16x8*)&sQ[w * 32 + 16 + l15][kk * 32 + quad * 8];
#pragma unroll
      for (int n = 0; n < 4; n++) {
        s16x8 bk = *(const s16x8*)&sK[n * 16 + l15][kk * 32 + quad * 8];
        sa[0][n] = MFMA_BF16(aq0, bk, sa[0][n]);
        sa[1][n] = MFMA_BF16(aq1, bk, sa[1][n]);
      }
    }
#pragma unroll
    for (int t = 0; t < 2; t++)
#pragma unroll
      for (int n = 0; n < 4; n++) {
        const size_t colg = (size_t)k0 + n * 16 + l15;
#pragma unroll
        for (int r = 0; r < 4; r++) {
          float p = __expf(sa[t][n][r] * 0.125f - m_s[t][r]) * inv_l[t][r];
          const int rl = w * 32 + t * 16 + quad * 4 + r;
          attn[((size_t)bh * 2048 + q0 + rl) * 2048 + colg] = p;
          sP[w][t * 16 + quad * 4 + r][n * 16 + l15] = f2bf(p);
        }
      }
    __syncthreads();
#pragma unroll
    for (int kk = 0; kk < 2; kk++) {
      s16x8 ap0 = *(const s16x8*)&sP[w][l15][kk * 32 + quad * 8];
      s16x8 ap1 = *(const s16x8*)&sP[w][16 + l15][kk * 32 + quad * 8];
#pragma unroll
      for (int d = 0; d < 4; d++) {
        s16x8 bv = *(const s16x8*)&sVt[d * 16 + l15][kk * 32 + quad * 8];
        oa[0][d] = MFMA_BF16(ap0, bv, oa[0][d]);
        oa[1][d] = MFMA_BF16(ap1, bv, oa[1][d]);
      }
    }
  }

  // write context values -> [b][s][h*64+d] bf16
  const int b = bh >> 4, h = bh & 15;
#pragma unroll
  for (int t = 0; t < 2; t++)
#pragma unroll
    for (int d = 0; d < 4; d++)
#pragma unroll
      for (int r = 0; r < 4; r++) {
        const int s_i = q0 + w * 32 + t * 16 + quad * 4 + r;
        vals[((size_t)b * 2048 + s_i) * 1024 + h * 64 + d * 16 + l15] = f2bf(oa[t][d][r]);
      }
}

// ---- GEMM2: values[8192x1024] @ WoutT + b_out -> out fp32 ----
__global__ __launch_bounds__(256) void gemm_out_k(
    const u16* __restrict__ A, const u16* __restrict__ Bt, const float* __restrict__ bias,
    float* __restrict__ out) {
  __shared__ alignas(16) u16 sA[128][40];
  __shared__ alignas(16) u16 sB[128][40];
  const int tid = threadIdx.x;
  const int w = tid >> 6, lane = tid & 63, quad = lane >> 4, l15 = lane & 15;
  const int m0 = blockIdx.x * 128, n0 = blockIdx.y * 128;
  const int mw = (w & 1) * 64, nw = (w >> 1) * 64;
  const f32x4 fz = {0.f, 0.f, 0.f, 0.f};
  f32x4 acc[4][4];
#pragma unroll
  for (int i = 0; i < 4; i++)
#pragma unroll
    for (int j = 0; j < 4; j++) acc[i][j] = fz;
  const int sr = tid >> 2, sc = (tid & 3) * 8;
  const u16* Ab = A + (size_t)(m0 + sr) * 1024 + sc;
  const u16* Bb = Bt + (size_t)(n0 + sr) * 1024 + sc;
  for (int k0 = 0; k0 < 1024; k0 += 32) {
    __syncthreads();
    *(s16x8*)&sA[sr][sc]      = *(const s16x8*)(Ab + k0);
    *(s16x8*)&sA[sr + 64][sc] = *(const s16x8*)(Ab + 64 * 1024 + k0);
    *(s16x8*)&sB[sr][sc]      = *(const s16x8*)(Bb + k0);
    *(s16x8*)&sB[sr + 64][sc] = *(const s16x8*)(Bb + 64 * 1024 + k0);
    __syncthreads();
    s16x8 af[4], bf[4];
#pragma unroll
    for (int i = 0; i < 4; i++) af[i] = *(const s16x8*)&sA[mw + i * 16 + l15][quad * 8];
#pragma unroll
    for (int j = 0; j < 4; j++) bf[j] = *(const s16x8*)&sB[nw + j * 16 + l15][quad * 8];
#pragma unroll
    for (int i = 0; i < 4; i++)
#pragma unroll
      for (int j = 0; j < 4; j++)
        acc[i][j] = MFMA_BF16(af[i], bf[j], acc[i][j]);
  }
#pragma unroll
  for (int j = 0; j < 4; j++) {
    const int ng = n0 + nw + j * 16 + l15;
    const float bv = bias[ng];
#pragma unroll
    for (int i = 0; i < 4; i++)
#pragma unroll
      for (int r = 0; r < 4; r++) {
        const int mg = m0 + mw + i * 16 + quad * 4 + r;
        out[(size_t)mg * 1024 + ng] = acc[i][j][r] + bv;
      }
  }
}

extern "C" void kernel_launch(void* const* d_in, const int* in_sizes, int n_in,
                              void* d_out, int out_size, void* d_ws, size_t ws_size,
                              hipStream_t stream) {
  const float* x    = (const float*)d_in[0];
  const float* Wqkv = (const float*)d_in[1];
  const float* bqkv = (const float*)d_in[2];
  const float* Wout = (const float*)d_in[3];
  const float* bout = (const float*)d_in[4];
  float* out  = (float*)d_out;
  float* attn = out + (size_t)8388608;  // output 0 is 4*2048*1024 fp32

  // workspace layout (bf16 elems): total ~75.5 MB
  u16* ws    = (u16*)d_ws;
  u16* xbf   = ws;                       // 8388608  (reused as `vals` after gemm_qkv)
  u16* WqkvT = ws + 8388608;             // 3145728
  u16* WoutT = WqkvT + 3145728;          // 1048576
  u16* qb    = WoutT + 1048576;          // 8388608
  u16* kb    = qb + 8388608;             // 8388608
  u16* vTb   = kb + 8388608;             // 8388608
  u16* vals  = xbf;                      // alias: xbf dead after gemm_qkv

  cvt_f32_bf16<<<dim3(8388608 / 4 / 256), dim3(256), 0, stream>>>(x, xbf, 8388608 / 4);
  transpose_cvt<<<dim3(96, 32), dim3(32, 8), 0, stream>>>(Wqkv, WqkvT, 1024, 3072);
  transpose_cvt<<<dim3(32, 32), dim3(32, 8), 0, stream>>>(Wout, WoutT, 1024, 1024);
  gemm_qkv<<<dim3(64, 24), dim3(256), 0, stream>>>(xbf, WqkvT, bqkv, qb, kb, vTb);
  attention_k<<<dim3(16, 64), dim3(256), 0, stream>>>(qb, kb, vTb, attn, vals);
  gemm_out_k<<<dim3(64, 8), dim3(256), 0, stream>>>(vals, WoutT, bout, out);
}